// Round 7
// baseline (619.568 us; speedup 1.0000x reference)
//
#include <hip/hip_runtime.h>

typedef unsigned short u16;
typedef unsigned int   u32;

typedef __attribute__((ext_vector_type(8))) __bf16 bf16x8;
typedef __attribute__((ext_vector_type(8))) unsigned short u16x8;
typedef __attribute__((ext_vector_type(4))) float  f32x4;

#define C      256
#define OUTC   128
#define LN_EPS 1e-5f

__device__ __forceinline__ float bf2f(u16 u) {
    u32 i = ((u32)u) << 16; float f; __builtin_memcpy(&f, &i, 4); return f;
}
__device__ __forceinline__ u16 f2bf(float f) {
    u32 i; __builtin_memcpy(&i, &f, 4);
    u32 r = (i + 0x7FFFu + ((i >> 16) & 1u)) >> 16;
    return (u16)r;
}
__device__ __forceinline__ void load_lds16(const void* g, void* l) {
    __builtin_amdgcn_global_load_lds((const __attribute__((address_space(1))) u32*)g,
                                     (__attribute__((address_space(3))) u32*)l, 16, 0, 0);
}

// ---- combined prep: weights (blocks < PREP_BLK) + x->bf16 cast (rest) ------------
#define PREP_BLK 1408   // (256*512 + 256*768 + 128*256) / 256
__global__ void prep_combo(const float* wl0, const float* w00, const float* w10,
                           const float* bl0, const float* b00, const float* b10,
                           const float* gate0,
                           const float* wl1, const float* w01, const float* w11,
                           const float* bl1, const float* b01, const float* b11,
                           const float* gate1,
                           const float* Wout, const float* x,
                           u16* __restrict__ WcatA, u16* __restrict__ WcatB,
                           u16* __restrict__ Woutb, float* __restrict__ bcat,
                           u16* __restrict__ xb, size_t n8)
{
    if (blockIdx.x >= PREP_BLK) {
        size_t i = ((size_t)(blockIdx.x - PREP_BLK) * 256 + threadIdx.x);
        if (i >= n8) return;
        const float* p = x + i * 8;
        float4 v0 = *(const float4*)p;
        float4 v1 = *(const float4*)(p + 4);
        u16x8 o;
        o[0] = f2bf(v0.x); o[1] = f2bf(v0.y); o[2] = f2bf(v0.z); o[3] = f2bf(v0.w);
        o[4] = f2bf(v1.x); o[5] = f2bf(v1.y); o[6] = f2bf(v1.z); o[7] = f2bf(v1.w);
        *(u16x8*)(xb + i * 8) = o;
        return;
    }
    int idx = blockIdx.x * 256 + threadIdx.x;
    float gA = 1.f / (1.f + expf(-gate1[0]));   // layer processed FIRST uses params *1
    float gB = 1.f / (1.f + expf(-gate0[0]));
    if (idx < 256 * 512) {
        int n = idx >> 9, k = idx & 511;
        float v;
        if (k < 256) v = wl1[n * 256 + k];
        else         v = (1.f - gA) * w01[n * 256 + (k - 256)] + gA * w11[n * 256 + (k - 256)];
        WcatA[idx] = f2bf(v);
    } else if (idx < 256 * 512 + 256 * 768) {
        int j = idx - 256 * 512;
        int n = j / 768, k = j - n * 768;
        float v;
        if (k < 256)      v = wl0[n * 256 + k];
        else if (k < 512) v = (1.f - gB) * w00[n * 256 + (k - 256)];
        else              v = gB * w10[n * 256 + (k - 512)];
        WcatB[j] = f2bf(v);
    } else {
        int j = idx - (256 * 512 + 256 * 768);
        if (j < OUTC * C) Woutb[j] = f2bf(Wout[j]);
    }
    if (idx < 512) {
        int nn = idx & 255;
        if (idx < 256) bcat[idx] = bl1[nn] + (1.f - gA) * b01[nn] + gA * b11[nn];
        else           bcat[idx] = bl0[nn] + (1.f - gB) * b00[nn] + gB * b10[nn];
    }
}

// ================= CSR build (both graphs per launch) =============================
__global__ void count_edges2(const int* __restrict__ ei1, const int* __restrict__ ei0,
                             int* __restrict__ cnt1, int* __restrict__ deg1,
                             int* __restrict__ cnt0, int* __restrict__ deg0,
                             int E, int Nn, int ebg)
{
    int b = blockIdx.x;
    const int* ei; int *cnt, *deg;
    if (b < ebg) { ei = ei1; cnt = cnt1; deg = deg1; }
    else         { b -= ebg; ei = ei0; cnt = cnt0; deg = deg0; }
    int idx = b * 256 + threadIdx.x;
    if (idx >= E) return;
    int s = ei[idx], d = ei[E + idx];
    if ((unsigned)s >= (unsigned)Nn || (unsigned)d >= (unsigned)Nn) return;
    atomicAdd(cnt + s, 1);
    atomicAdd(deg + d, 1);
}

__global__ void block_sums2(const int* __restrict__ cnt1, const int* __restrict__ cnt0,
                            int* __restrict__ parts1, int* __restrict__ parts0,
                            int n, int nblk)
{
    int b = blockIdx.x;
    const int* counts; int* partials;
    if (b < nblk) { counts = cnt1; partials = parts1; }
    else          { b -= nblk; counts = cnt0; partials = parts0; }
    int i = b * 256 + threadIdx.x;
    int v = (i < n) ? counts[i] : 0;
    #pragma unroll
    for (int off = 32; off; off >>= 1) v += __shfl_down(v, off, 64);
    __shared__ int ws[4];
    if ((threadIdx.x & 63) == 0) ws[threadIdx.x >> 6] = v;
    __syncthreads();
    if (threadIdx.x == 0) partials[b] = ws[0] + ws[1] + ws[2] + ws[3];
}

__global__ void scan_partials2(int* __restrict__ parts1, int* __restrict__ parts0, int nblk)
{
    int* partials = blockIdx.x ? parts0 : parts1;
    __shared__ int buf[1024];
    int tid = threadIdx.x;
    int v = (tid < nblk) ? partials[tid] : 0;
    buf[tid] = v; __syncthreads();
    for (int off = 1; off < 1024; off <<= 1) {
        int t = (tid >= off) ? buf[tid - off] : 0;
        __syncthreads();
        buf[tid] += t;
        __syncthreads();
    }
    if (tid < nblk) partials[tid] = buf[tid] - v;
}

__global__ void make_offsets2(int* __restrict__ cnt1, int* __restrict__ cnt0,
                              const int* __restrict__ parts1, const int* __restrict__ parts0,
                              int* __restrict__ off1a, int* __restrict__ off0a,
                              int n, int nblk)
{
    int b = blockIdx.x;
    int* counts_cursor; const int* partials; int* offsets;
    if (b < nblk) { counts_cursor = cnt1; partials = parts1; offsets = off1a; }
    else          { b -= nblk; counts_cursor = cnt0; partials = parts0; offsets = off0a; }
    __shared__ int buf[256];
    int i = b * 256 + threadIdx.x;
    int cnt = (i < n) ? counts_cursor[i] : 0;
    buf[threadIdx.x] = cnt; __syncthreads();
    for (int off = 1; off < 256; off <<= 1) {
        int t = (threadIdx.x >= off) ? buf[threadIdx.x - off] : 0;
        __syncthreads();
        buf[threadIdx.x] += t;
        __syncthreads();
    }
    int off = partials[b] + buf[threadIdx.x] - cnt;
    if (i < n) {
        offsets[i] = off;
        counts_cursor[i] = off;
        if (i == n - 1) offsets[n] = off + cnt;
    }
}

__global__ void fill_edges2(const int* __restrict__ ei1, const int* __restrict__ ei0,
                            int* __restrict__ cur1, int* __restrict__ cur0,
                            int* __restrict__ ed1, int* __restrict__ ed0,
                            int E, int Nn, int ebg)
{
    int b = blockIdx.x;
    const int* ei; int *cursor, *edgedst;
    if (b < ebg) { ei = ei1; cursor = cur1; edgedst = ed1; }
    else         { b -= ebg; ei = ei0; cursor = cur0; edgedst = ed0; }
    int idx = b * 256 + threadIdx.x;
    if (idx >= E) return;
    int s = ei[idx], d = ei[E + idx];
    if ((unsigned)s >= (unsigned)Nn || (unsigned)d >= (unsigned)Nn) return;
    int p = atomicAdd(cursor + s, 1);
    edgedst[p] = d;
}

// ---- gather: one wave per node; lanes 0-31 / 32-63 cover 2 edges, 16B per lane ---
__global__ __launch_bounds__(256) void gather_kernel(
    const int* __restrict__ offsets, const int* __restrict__ edgedst,
    const int* __restrict__ degcnt, const u16* __restrict__ h,
    u16* __restrict__ aggb, int Nn)
{
    int node = blockIdx.x * 4 + (threadIdx.x >> 6);
    if (node >= Nn) return;
    int lane = threadIdx.x & 63;
    int half = lane >> 5, l5 = lane & 31;
    int beg = offsets[node], end = offsets[node + 1];
    float a0[8] = {}, a1[8] = {};
    int p = beg;
    for (; p + 3 < end; p += 4) {              // 4 edges in flight
        int d0 = edgedst[p + half];
        int d1 = edgedst[p + 2 + half];
        u16x8 v0 = *(const u16x8*)(h + (size_t)d0 * C + l5 * 8);
        u16x8 v1 = *(const u16x8*)(h + (size_t)d1 * C + l5 * 8);
        #pragma unroll
        for (int j = 0; j < 8; ++j) { a0[j] += bf2f(v0[j]); a1[j] += bf2f(v1[j]); }
    }
    if (p + 1 < end) {                         // remaining pair
        int d0 = edgedst[p + half];
        u16x8 v0 = *(const u16x8*)(h + (size_t)d0 * C + l5 * 8);
        #pragma unroll
        for (int j = 0; j < 8; ++j) a0[j] += bf2f(v0[j]);
        p += 2;
    }
    if (p < end && half == 0) {                // odd tail: lanes 0-31 only
        int d0 = edgedst[p];
        u16x8 v0 = *(const u16x8*)(h + (size_t)d0 * C + l5 * 8);
        #pragma unroll
        for (int j = 0; j < 8; ++j) a1[j] += bf2f(v0[j]);
    }
    float inv = 1.0f / fmaxf((float)degcnt[node], 1.0f);
    u16x8 o;
    #pragma unroll
    for (int j = 0; j < 8; ++j) {
        float s = a0[j] + a1[j];
        s += __shfl_xor(s, 32);                // combine edge-halves
        o[j] = f2bf(s * inv);
    }
    if (half == 0)
        *(u16x8*)(aggb + (size_t)node * C + l5 * 8) = o;
}

// =================================================================================
// layer_gemm9: 128x256 tile, BK=32, 3-buffer rotation, prefetch distance 2
// (vmcnt(6): 9 loads = 3 tiles in flight), 2 blocks/CU (LDS 76KB, regs <=128 via
// __launch_bounds__(512,4)) so cross-block waves cover barrier/vmcnt stalls.
// Fused bias+ReLU+LN; if FUSE, out-projection via two 64-row LDS strips (32KB,
// reusing the dead A/B buffers) with Wout B-frags read from global (L2-hot).
// LDS tile swizzle: pair-row scheme, phys 16B-chunk = (((r&1)<<2)|q) ^ ((r>>1)&7).
// global_load_lds dest is linear; swizzle applied on the GLOBAL source address.
// =================================================================================
template <int NSEG, bool FUSE>
__global__ __launch_bounds__(512, 4) void layer_gemm9(
    const u16* __restrict__ s0, const u16* __restrict__ s1, const u16* __restrict__ s2,
    const u16* __restrict__ W,          // [256][NSEG*256] bf16
    const float* __restrict__ bcat,
    const float* __restrict__ lns, const float* __restrict__ lnb,
    u16* __restrict__ Hout,
    const u16* __restrict__ WoutB, const float* __restrict__ boutp,
    float* __restrict__ outp, int Nnodes)
{
    constexpr int WK = NSEG * 256;
    constexpr int T  = NSEG * 8;               // K-tiles of 32

    extern __shared__ char smem[];
    u16*   A_e    = (u16*)smem;                // 3 x 4096 elems (24 KB)
    u16*   B_e    = (u16*)(smem + 24576);      // 3 x 8192 elems (48 KB)
    float* lnpart = (float*)(smem + 73728);    // [128][4][2] (4 KB)
    u16*   h2s    = (u16*)smem;                // FUSE strip: 64x256 bf16 (32 KB)

    const int tid  = threadIdx.x;
    const int wave = tid >> 6, lane = tid & 63;
    const int wave_m = wave & 1, wave_n = wave >> 1;   // 2 x 4
    const int q = lane >> 4, l15 = lane & 15;
    const int m0 = blockIdx.x * 128;

    // ---- staging addresses: A = 1 load/thread (8KB tile), B = 2 (16KB tile) ----
    size_t a_goff; int aldso;
    {
        int o = wave * 1024 + lane * 16;               // linear byte off in A tile
        int g = o >> 7, slot = (o >> 4) & 7;
        int bc = slot ^ (g & 7);
        int r = 2 * g + (bc >> 2), c = bc & 3;         // logical row/chunk at o
        int node = m0 + r; if (node >= Nnodes) node = Nnodes - 1;
        a_goff = (size_t)node * C + c * 8;
        aldso  = wave * 1024;
    }
    size_t b_goff[2]; int bldso[2];
    #pragma unroll
    for (int i = 0; i < 2; ++i) {
        int o = i * 8192 + wave * 1024 + lane * 16;    // linear byte off in B tile
        int g = o >> 7, slot = (o >> 4) & 7;
        int bc = slot ^ (g & 7);
        int r = 2 * g + (bc >> 2), c = bc & 3;
        b_goff[i] = (size_t)r * WK + c * 8;
        bldso[i]  = i * 8192 + wave * 1024;
    }

    // ---- fragment read offsets (elements within one tile) ----
    int aoffE[4], boffE[4];
    #pragma unroll
    for (int j = 0; j < 4; ++j) {
        int r = wave_m * 64 + j * 16 + l15;
        aoffE[j] = (r >> 1) * 64 + (((((r & 1) << 2) | q) ^ ((r >> 1) & 7)) << 3);
        int rb = wave_n * 64 + j * 16 + l15;
        boffE[j] = (rb >> 1) * 64 + (((((rb & 1) << 2) | q) ^ ((rb >> 1) & 7)) << 3);
    }

    f32x4 acc[4][4] = {};

    auto stage = [&](int bi, int t) {
        const u16* sp = (t < 8) ? s0 : ((NSEG == 2 || t < 16) ? s1 : s2);
        load_lds16(sp + ((t & 7) << 5) + a_goff, (char*)A_e + bi * 8192 + aldso);
        const u16* wb = W + (t << 5);
        load_lds16(wb + b_goff[0], (char*)B_e + bi * 16384 + bldso[0]);
        load_lds16(wb + b_goff[1], (char*)B_e + bi * 16384 + bldso[1]);
    };
    auto compute = [&](const u16* Ac, const u16* Bc) {
        bf16x8 af[4], bfr[4];
        #pragma unroll
        for (int f = 0; f < 4; ++f) bfr[f] = *(const bf16x8*)(Bc + boffE[f]);
        #pragma unroll
        for (int j = 0; j < 4; ++j) af[j] = *(const bf16x8*)(Ac + aoffE[j]);
        __builtin_amdgcn_s_setprio(1);
        #pragma unroll
        for (int j = 0; j < 4; ++j)
            #pragma unroll
            for (int f = 0; f < 4; ++f)
                acc[j][f] = __builtin_amdgcn_mfma_f32_16x16x32_bf16(af[j], bfr[f], acc[j][f], 0, 0, 0);
        __builtin_amdgcn_s_setprio(0);
    };

    // prologue: tiles 0,1,2 in flight (9 loads/wave)
    stage(0, 0); stage(1, 1); stage(2, 2);
    int bi = 0;
    for (int t = 0; t < T; ++t) {
        if (t < T - 2)       asm volatile("s_waitcnt vmcnt(6)" ::: "memory");
        else if (t == T - 2) asm volatile("s_waitcnt vmcnt(3)" ::: "memory");
        else                 asm volatile("s_waitcnt vmcnt(0)" ::: "memory");
        asm volatile("s_barrier" ::: "memory");
        __builtin_amdgcn_sched_barrier(0);
        compute(A_e + bi * 4096, B_e + bi * 8192);
        asm volatile("s_barrier" ::: "memory");        // all waves done reading buf bi
        if (t + 3 < T) stage(bi, t + 3);               // refill same buffer, 2 phases ahead
        bi = (bi == 2) ? 0 : bi + 1;
    }

    // ---- fused epilogue: bias + relu + LN ----
    float bias[4], lsc[4], lbi[4];
    #pragma unroll
    for (int f = 0; f < 4; ++f) {
        int n = wave_n * 64 + f * 16 + l15;
        bias[f] = bcat[n]; lsc[f] = lns[n]; lbi[f] = lnb[n];
    }
    #pragma unroll
    for (int j = 0; j < 4; ++j)
        #pragma unroll
        for (int r = 0; r < 4; ++r) {
            float p = 0.f, pp = 0.f;
            #pragma unroll
            for (int f = 0; f < 4; ++f) {
                float v = acc[j][f][r] + bias[f];
                v = fmaxf(v, 0.f);
                acc[j][f][r] = v;
                p += v; pp += v * v;
            }
            #pragma unroll
            for (int off = 1; off < 16; off <<= 1) {
                p  += __shfl_xor(p,  off, 16);
                pp += __shfl_xor(pp, off, 16);
            }
            if (l15 == 0) {
                int row = wave_m * 64 + j * 16 + q * 4 + r;
                lnpart[row * 8 + wave_n * 2 + 0] = p;
                lnpart[row * 8 + wave_n * 2 + 1] = pp;
            }
        }
    __syncthreads();
    #pragma unroll
    for (int j = 0; j < 4; ++j)
        #pragma unroll
        for (int r = 0; r < 4; ++r) {
            int row = wave_m * 64 + j * 16 + q * 4 + r;
            int node = m0 + row;
            float S1 = lnpart[row * 8 + 0] + lnpart[row * 8 + 2]
                     + lnpart[row * 8 + 4] + lnpart[row * 8 + 6];
            float S2 = lnpart[row * 8 + 1] + lnpart[row * 8 + 3]
                     + lnpart[row * 8 + 5] + lnpart[row * 8 + 7];
            float mean = S1 * (1.f / 256.f);
            float var  = fmaxf(S2 * (1.f / 256.f) - mean * mean, 0.f);
            float rstd = rsqrtf(var + LN_EPS);
            if constexpr (FUSE) {
                #pragma unroll
                for (int f = 0; f < 4; ++f)
                    acc[j][f][r] = (acc[j][f][r] - mean) * rstd * lsc[f] + lbi[f];
            } else if (node < Nnodes) {
                u16* op = Hout + (size_t)node * C;
                #pragma unroll
                for (int f = 0; f < 4; ++f) {
                    int n = wave_n * 64 + f * 16 + l15;
                    op[n] = f2bf((acc[j][f][r] - mean) * rstd * lsc[f] + lbi[f]);
                }
            }
        }

    if constexpr (FUSE) {
        // ---- out-projection via two 64-row strips: out = h2 @ WoutB^T + bout ----
        const int m2 = wave & 1, n2 = wave >> 1;
        float b2[2];
        #pragma unroll
        for (int f2 = 0; f2 < 2; ++f2) b2[f2] = boutp[n2 * 32 + f2 * 16 + l15];
        #pragma unroll
        for (int s = 0; s < 2; ++s) {
            __syncthreads();            // strip buffer free (K-loop / prev strip done)
            if (wave_m == s) {          // writer waves: rows s*64 .. s*64+63
                #pragma unroll
                for (int j = 0; j < 4; ++j)
                    #pragma unroll
                    for (int r = 0; r < 4; ++r) {
                        int rowl = j * 16 + q * 4 + r;
                        #pragma unroll
                        for (int f = 0; f < 4; ++f) {
                            int n = wave_n * 64 + f * 16 + l15;
                            h2s[rowl * 256 + ((((n >> 3) ^ (rowl & 15)) << 3) | (n & 7))]
                                = f2bf(acc[j][f][r]);
                        }
                    }
            }
            __syncthreads();            // strip complete
            f32x4 acc2[2][2] = {};
            for (int kt = 0; kt < 8; ++kt) {
                bf16x8 bw[2];
                #pragma unroll
                for (int f2 = 0; f2 < 2; ++f2)
                    bw[f2] = *(const bf16x8*)(WoutB
                              + (size_t)(n2 * 32 + f2 * 16 + l15) * 256 + kt * 32 + q * 8);
                #pragma unroll
                for (int mf2 = 0; mf2 < 2; ++mf2) {
                    int rr = m2 * 32 + mf2 * 16 + l15;
                    int ch = ((kt << 2) | q) ^ (rr & 15);
                    bf16x8 a = *(const bf16x8*)(h2s + rr * 256 + (ch << 3));
                    #pragma unroll
                    for (int f2 = 0; f2 < 2; ++f2)
                        acc2[mf2][f2] = __builtin_amdgcn_mfma_f32_16x16x32_bf16(
                            a, bw[f2], acc2[mf2][f2], 0, 0, 0);
                }
            }
            #pragma unroll
            for (int mf2 = 0; mf2 < 2; ++mf2)
                #pragma unroll
                for (int r = 0; r < 4; ++r) {
                    int row = s * 64 + m2 * 32 + mf2 * 16 + q * 4 + r;
                    int node = m0 + row;
                    if (node < Nnodes) {
                        float* op = outp + (size_t)node * OUTC;
                        #pragma unroll
                        for (int f2 = 0; f2 < 2; ++f2)
                            op[n2 * 32 + f2 * 16 + l15] = acc2[mf2][f2][r] + b2[f2];
                    }
                }
        }
    }
}

extern "C" void kernel_launch(void* const* d_in, const int* in_sizes, int n_in,
                              void* d_out, int out_size, void* d_ws, size_t ws_size,
                              hipStream_t stream)
{
    const float* x    = (const float*)d_in[0];
    const int*   ei0  = (const int*)d_in[1];
    const int*   ei1  = (const int*)d_in[2];
    const float* wl0  = (const float*)d_in[3];
    const float* bl0  = (const float*)d_in[4];
    const float* w00  = (const float*)d_in[5];
    const float* b00  = (const float*)d_in[6];
    const float* w10  = (const float*)d_in[7];
    const float* b10  = (const float*)d_in[8];
    const float* gate0= (const float*)d_in[9];
    const float* lns0 = (const float*)d_in[10];
    const float* lnb0 = (const float*)d_in[11];
    const float* wl1  = (const float*)d_in[12];
    const float* bl1  = (const float*)d_in[13];
    const float* w01  = (const float*)d_in[14];
    const float* b01  = (const float*)d_in[15];
    const float* w11  = (const float*)d_in[16];
    const float* b11  = (const float*)d_in[17];
    const float* gate1= (const float*)d_in[18];
    const float* lns1 = (const float*)d_in[19];
    const float* lnb1 = (const float*)d_in[20];
    const float* Wout = (const float*)d_in[21];
    const float* bout = (const float*)d_in[22];

    const int N = in_sizes[0] / C;     // 100000
    const int E = in_sizes[1] / 2;     // 400000

    // workspace (~161 MiB)
    char* w = (char*)d_ws;
    u16*   WcatA = (u16*)w;   w += (size_t)256 * 512 * 2;
    u16*   WcatB = (u16*)w;   w += (size_t)256 * 768 * 2;
    u16*   Woutb = (u16*)w;   w += (size_t)OUTC * C * 2;
    float* bcat  = (float*)w; w += 4096;
    int*   cnt1  = (int*)w;   w += (size_t)N * 4;       // 4 contiguous, one memset
    int*   deg1  = (int*)w;   w += (size_t)N * 4;
    int*   cnt0  = (int*)w;   w += (size_t)N * 4;
    int*   deg0  = (int*)w;   w += (size_t)N * 4;
    int*   off1  = (int*)w;   w += (((size_t)(N + 1) * 4) + 255) & ~255ull;
    int*   off0  = (int*)w;   w += (((size_t)(N + 1) * 4) + 255) & ~255ull;
    int*   parts1= (int*)w;   w += 4096;
    int*   parts0= (int*)w;   w += 4096;
    int*   ed1   = (int*)w;   w += (size_t)E * 4;
    int*   ed0   = (int*)w;   w += (size_t)E * 4;
    u16*   xb    = (u16*)w;   w += (size_t)N * C * 2;   // 51.2 MB bf16 copy of x
    u16*   aggb  = (u16*)w;   w += (size_t)N * C * 2;   // 51.2 MB (reused both layers)
    u16*   h1    = (u16*)w;   w += (size_t)N * C * 2;   // 51.2 MB

    const int eb_grid = (E + 255) / 256;
    const int nblk    = (N + 255) / 256;                // 391 <= 1024
    const int gt_grid = (N + 3) / 4;
    const int gm9     = (N + 127) / 128;                // 782 blocks, 128-row tiles
    const size_t n8   = (size_t)N * C / 8;
    const int xc_blk  = (int)((n8 + 255) / 256);
    const size_t lds9 = 77824;                          // 24K A + 48K B + 4K lnpart

    hipMemsetAsync(cnt1, 0, (size_t)4 * N * 4, stream);
    prep_combo<<<PREP_BLK + xc_blk, 256, 0, stream>>>(
        wl0, w00, w10, bl0, b00, b10, gate0,
        wl1, w01, w11, bl1, b01, b11, gate1,
        Wout, x, WcatA, WcatB, Woutb, bcat, xb, n8);

    // ---- CSR builds, both graphs per launch ----
    count_edges2 <<<2 * eb_grid, 256, 0, stream>>>(ei1, ei0, cnt1, deg1, cnt0, deg0, E, N, eb_grid);
    block_sums2  <<<2 * nblk, 256, 0, stream>>>(cnt1, cnt0, parts1, parts0, N, nblk);
    scan_partials2<<<2, 1024, 0, stream>>>(parts1, parts0, nblk);
    make_offsets2<<<2 * nblk, 256, 0, stream>>>(cnt1, cnt0, parts1, parts0, off1, off0, N, nblk);
    fill_edges2  <<<2 * eb_grid, 256, 0, stream>>>(ei1, ei0, cnt1, cnt0, ed1, ed0, E, N, eb_grid);

    // ---- layer A: graph ei1, params *1, h = x0 = xb; K = 512 (w0,w1 folded) ----
    gather_kernel<<<gt_grid, 256, 0, stream>>>(off1, ed1, deg1, xb, aggb, N);
    layer_gemm9<2, false><<<gm9, 512, lds9, stream>>>(aggb, xb, nullptr, WcatA, bcat,
                                                      lns1, lnb1, h1,
                                                      nullptr, nullptr, nullptr, N);

    // ---- layer B + fused output projection: graph ei0, params *0 ----
    gather_kernel<<<gt_grid, 256, 0, stream>>>(off0, ed0, deg0, h1, aggb, N);
    layer_gemm9<3, true><<<gm9, 512, lds9, stream>>>(aggb, h1, xb, WcatB, bcat + C,
                                                     lns0, lnb0, nullptr,
                                                     Woutb, bout, (float*)d_out, N);
}